// Round 1
// baseline (242.420 us; speedup 1.0000x reference)
//
#include <hip/hip_runtime.h>
#include <hip/hip_bf16.h>
#include <cmath>

typedef __bf16 bf16_t;
typedef __bf16 bf16x8 __attribute__((ext_vector_type(8)));
typedef float  f32x4  __attribute__((ext_vector_type(4)));

#define AS1(p) ((__attribute__((address_space(1))) void*)(p))
#define AS3(p) ((__attribute__((address_space(3))) void*)(p))

// ---------------------------------------------------------------- constants
// N=8192, H=512, TAU=0.5, EPS=1e-8
// exp(x) = exp2(x * log2e); combined scale: (1/TAU)*log2e = 2*1.442695...
#define C_EXP2 2.8853900817779268f
#define NROWS  8192
#define HDIM   512

// ---------------------------------------------------------------- f32->bf16
__global__ __launch_bounds__(256) void cvt_f32_bf16(const float* __restrict__ src,
                                                    bf16_t* __restrict__ dst, int n8) {
    int i = blockIdx.x * 256 + threadIdx.x;
    if (i >= n8) return;
    const f32x4* s4 = (const f32x4*)src;
    f32x4 a = s4[2 * (size_t)i];
    f32x4 b = s4[2 * (size_t)i + 1];
    bf16x8 o;
#pragma unroll
    for (int j = 0; j < 4; ++j) { o[j] = (bf16_t)a[j]; o[4 + j] = (bf16_t)b[j]; }
    *(bf16x8*)(dst + 8 * (size_t)i) = o;
}

// ---------------------------------------------------------------- GEMM (NT)
// C[i][j] = sum_k A[i*K+k] * B[j*K+k],  K multiple of 32, M/N multiples of 128.
// 128x128 tile, BK=32, 4 waves (2x2), each wave 64x64 via 4x4 16x16x32 MFMAs.
// EPI=1: bias+ELU -> bf16 out (ldc=512)
// EPI=2: bias -> f32 out (d_out) + bf16 copy (ldc=512)
// EPI=3: e=exp2(acc*rn0*rn1*C); per-row partial sums of e and e*pos -> pS/pP
template <int EPI>
__global__ __launch_bounds__(256)
void gemm_bt(const bf16_t* __restrict__ A, const bf16_t* __restrict__ B, int K,
             const float* __restrict__ bias,
             bf16_t* __restrict__ outb, float* __restrict__ outf,
             const float* __restrict__ rn0, const float* __restrict__ rn1,
             const float* __restrict__ pos,
             float* __restrict__ pS, float* __restrict__ pP, int Mrows) {
    __shared__ __align__(16) bf16_t As[128 * 32];
    __shared__ __align__(16) bf16_t Bs[128 * 32];

    const int tid  = threadIdx.x;
    const int lane = tid & 63;
    const int wv   = tid >> 6;   // 0..3
    const int wm   = wv >> 1;    // wave row (0..1)
    const int wn   = wv & 1;     // wave col (0..1)
    const long ibase = (long)blockIdx.x * 128;
    const long jbase = (long)blockIdx.y * 128;

    f32x4 acc[4][4] = {};

    const int srow = lane >> 2;        // 0..15 within a 16-row chunk
    const int scol = (lane & 3) << 3;  // 0,8,16,24

    for (int k0 = 0; k0 < K; k0 += 32) {
        // stage A,B tiles: global_load_lds 16B/lane, wave-uniform LDS base
#pragma unroll
        for (int s = 0; s < 2; ++s) {
            const int chunk = s * 4 + wv;           // 0..7, 16 rows each
            const int row   = chunk * 16 + srow;
            __builtin_amdgcn_global_load_lds(AS1(A + (ibase + row) * (long)K + k0 + scol),
                                             AS3(&As[chunk * 512]), 16, 0, 0);
            __builtin_amdgcn_global_load_lds(AS1(B + (jbase + row) * (long)K + k0 + scol),
                                             AS3(&Bs[chunk * 512]), 16, 0, 0);
        }
        __syncthreads();  // drains vmcnt before reads

        bf16x8 af[4], bfr[4];
#pragma unroll
        for (int m = 0; m < 4; ++m)
            af[m] = *(const bf16x8*)&As[(wm * 64 + m * 16 + (lane & 15)) * 32 + ((lane >> 4) << 3)];
#pragma unroll
        for (int n = 0; n < 4; ++n)
            bfr[n] = *(const bf16x8*)&Bs[(wn * 64 + n * 16 + (lane & 15)) * 32 + ((lane >> 4) << 3)];
#pragma unroll
        for (int m = 0; m < 4; ++m)
#pragma unroll
            for (int n = 0; n < 4; ++n)
                acc[m][n] = __builtin_amdgcn_mfma_f32_16x16x32_bf16(af[m], bfr[n], acc[m][n], 0, 0, 0);
        __syncthreads();  // protect LDS overwrite next iter
    }

    // D mapping (m89-verified): col = lane&15, row = (lane>>4)*4 + reg
    const int crow = (lane >> 4) << 2;
    const int ccol = lane & 15;

    if constexpr (EPI == 1 || EPI == 2) {
#pragma unroll
        for (int m = 0; m < 4; ++m) {
            const long rowb = ibase + wm * 64 + m * 16 + crow;
#pragma unroll
            for (int n = 0; n < 4; ++n) {
                const int col = (int)jbase + wn * 64 + n * 16 + ccol;
                const float bv = bias[col];
#pragma unroll
                for (int r = 0; r < 4; ++r) {
                    float v = acc[m][n][r] + bv;
                    const long idx = (rowb + r) * HDIM + col;
                    if constexpr (EPI == 1) {
                        v = v > 0.f ? v : expm1f(v);  // ELU(alpha=1)
                        outb[idx] = (bf16_t)v;
                    } else {
                        outf[idx] = v;
                        outb[idx] = (bf16_t)v;
                    }
                }
            }
        }
    } else {
        __shared__ float sredS[4][64];
        __shared__ float sredP[4][64];
        float r1v[4];
#pragma unroll
        for (int n = 0; n < 4; ++n) r1v[n] = rn1[jbase + wn * 64 + n * 16 + ccol];
#pragma unroll
        for (int m = 0; m < 4; ++m) {
#pragma unroll
            for (int r = 0; r < 4; ++r) {
                const long row = ibase + wm * 64 + m * 16 + crow + r;
                const float r0 = rn0[row] * C_EXP2;
                float eS = 0.f, eP = 0.f;
#pragma unroll
                for (int n = 0; n < 4; ++n) {
                    const long col = jbase + wn * 64 + n * 16 + ccol;
                    const float e = exp2f(acc[m][n][r] * r0 * r1v[n]);
                    eS += e;
                    eP += e * pos[row * (long)NROWS + col];
                }
                // reduce across the 16-lane column group (masks stay in-group)
#pragma unroll
                for (int off = 8; off > 0; off >>= 1) {
                    eS += __shfl_xor(eS, off);
                    eP += __shfl_xor(eP, off);
                }
                if ((lane & 15) == 0) {
                    sredS[wv][m * 16 + crow + r] = eS;
                    sredP[wv][m * 16 + crow + r] = eP;
                }
            }
        }
        __syncthreads();
        if (tid < 128) {
            const int rr  = tid;
            const int wmr = rr >> 6;
            const float S = sredS[wmr * 2][rr & 63] + sredS[wmr * 2 + 1][rr & 63];
            const float P = sredP[wmr * 2][rr & 63] + sredP[wmr * 2 + 1][rr & 63];
            pS[(long)blockIdx.y * Mrows + ibase + rr] = S;
            pP[(long)blockIdx.y * Mrows + ibase + rr] = P;
        }
    }
}

// ---------------------------------------------------------------- row norms
// rn[i] = 1/||Z_i||, Z bf16 [16384][512]; one wave per row
__global__ __launch_bounds__(256) void rownorm(const bf16_t* __restrict__ Z,
                                               float* __restrict__ rn) {
    const int row  = blockIdx.x * 4 + (threadIdx.x >> 6);
    const int lane = threadIdx.x & 63;
    bf16x8 v = *(const bf16x8*)&Z[(size_t)row * HDIM + lane * 8];
    float s = 0.f;
#pragma unroll
    for (int j = 0; j < 8; ++j) { float f = (float)v[j]; s += f * f; }
#pragma unroll
    for (int off = 32; off > 0; off >>= 1) s += __shfl_xor(s, off);
    if (lane == 0) rn[row] = rsqrtf(s);
}

// ---------------------------------------------------------------- reductions
__global__ __launch_bounds__(256) void reduce_rows(const float* __restrict__ pS,
                                                   const float* __restrict__ pP,
                                                   float* __restrict__ bsum) {
    const int i = blockIdx.x * 256 + threadIdx.x;  // row 0..8191
    float S = 0.f, P = 0.f;
    for (int jb = 0; jb < 64; ++jb) {
        S += pS[jb * NROWS + i];
        P += pP[jb * NROWS + i];
    }
    float t = logf(P / (S + 1e-8f) + 1e-8f);
#pragma unroll
    for (int off = 32; off > 0; off >>= 1) t += __shfl_xor(t, off);
    __shared__ float red[4];
    if ((threadIdx.x & 63) == 0) red[threadIdx.x >> 6] = t;
    __syncthreads();
    if (threadIdx.x == 0) bsum[blockIdx.x] = red[0] + red[1] + red[2] + red[3];
}

__global__ void finalize(const float* __restrict__ bsum, float* __restrict__ loss) {
    float t = (threadIdx.x < 32) ? bsum[threadIdx.x] : 0.f;
#pragma unroll
    for (int off = 32; off > 0; off >>= 1) t += __shfl_xor(t, off);
    if (threadIdx.x == 0) *loss = -(t * (1.0f / 8192.0f));
}

// ---------------------------------------------------------------- launch
extern "C" void kernel_launch(void* const* d_in, const int* in_sizes, int n_in,
                              void* d_out, int out_size, void* d_ws, size_t ws_size,
                              hipStream_t stream) {
    const float* embd0 = (const float*)d_in[0];
    const float* embd1 = (const float*)d_in[1];
    const float* pos   = (const float*)d_in[2];
    const float* W1    = (const float*)d_in[3];
    const float* b1    = (const float*)d_in[4];
    const float* W2    = (const float*)d_in[5];
    const float* b2    = (const float*)d_in[6];
    float* out = (float*)d_out;  // [z0 (8192*512) | z1 (8192*512) | loss (1)]

    char* ws = (char*)d_ws;
    bf16_t* Xb   = (bf16_t*)(ws);               // 16 MB  [16384][512] bf16
    bf16_t* Hb   = (bf16_t*)(ws + 16777216);    // 16 MB
    bf16_t* Zb   = (bf16_t*)(ws + 33554432);    // 16 MB
    bf16_t* W1b  = (bf16_t*)(ws + 50331648);    // 512 KB
    bf16_t* W2b  = (bf16_t*)(ws + 50855936);    // 512 KB
    float*  rn   = (float*)(ws + 51380224);     // 64 KB  (rn0 | rn1)
    float*  pS   = (float*)(ws + 51445760);     // 2 MB   [64][8192]
    float*  pP   = (float*)(ws + 53542912);     // 2 MB
    float*  bsum = (float*)(ws + 55640064);     // 128 B

    // bf16 conversions (embd0‖embd1 stacked -> one [16384,512] matrix)
    cvt_f32_bf16<<<2048, 256, 0, stream>>>(embd0, Xb, 524288);
    cvt_f32_bf16<<<2048, 256, 0, stream>>>(embd1, Xb + 4194304, 524288);
    cvt_f32_bf16<<<128, 256, 0, stream>>>(W1, W1b, 32768);
    cvt_f32_bf16<<<128, 256, 0, stream>>>(W2, W2b, 32768);

    // H = ELU(X @ W1^T + b1)           [16384,512] bf16
    gemm_bt<1><<<dim3(128, 4), 256, 0, stream>>>(Xb, W1b, HDIM, b1, Hb, nullptr,
                                                 nullptr, nullptr, nullptr, nullptr, nullptr, 0);
    // Z = H @ W2^T + b2                f32 -> d_out (z0|z1), bf16 -> Zb
    gemm_bt<2><<<dim3(128, 4), 256, 0, stream>>>(Hb, W2b, HDIM, b2, Zb, out,
                                                 nullptr, nullptr, nullptr, nullptr, nullptr, 0);
    // rn[i] = 1/||Z_i||
    rownorm<<<4096, 256, 0, stream>>>(Zb, rn);
    // dot = z0 @ z1^T fused with exp(cos/tau) and row partial sums vs pos
    gemm_bt<3><<<dim3(64, 64), 256, 0, stream>>>(Zb, Zb + 4194304, HDIM, nullptr,
                                                 nullptr, nullptr, rn, rn + NROWS, pos,
                                                 pS, pP, NROWS);
    // per-row S,P -> t_i -> block sums -> loss
    reduce_rows<<<32, 256, 0, stream>>>(pS, pP, bsum);
    finalize<<<1, 64, 0, stream>>>(bsum, out + 8388608);
}

// Round 2
// 214.218 us; speedup vs baseline: 1.1316x; 1.1316x over previous
//
#include <hip/hip_runtime.h>
#include <hip/hip_bf16.h>
#include <cmath>

typedef __bf16 bf16_t;
typedef __bf16 bf16x8 __attribute__((ext_vector_type(8)));
typedef float  f32x4  __attribute__((ext_vector_type(4)));

#define AS1(p) ((__attribute__((address_space(1))) void*)(p))
#define AS3(p) ((__attribute__((address_space(3))) void*)(p))

// N=8192, H=512, TAU=0.5, EPS=1e-8
// exp(x) = exp2(x * log2e / TAU); (1/0.5)*log2e = 2.885390...
#define C_EXP2 2.8853900817779268f
#define NROWS  8192
#define HDIM   512

// ---------------------------------------------------------------- f32->bf16
__global__ __launch_bounds__(256) void cvt_f32_bf16(const float* __restrict__ src,
                                                    bf16_t* __restrict__ dst, int n8) {
    int i = blockIdx.x * 256 + threadIdx.x;
    if (i >= n8) return;
    const f32x4* s4 = (const f32x4*)src;
    f32x4 a = s4[2 * (size_t)i];
    f32x4 b = s4[2 * (size_t)i + 1];
    bf16x8 o;
#pragma unroll
    for (int j = 0; j < 4; ++j) { o[j] = (bf16_t)a[j]; o[4 + j] = (bf16_t)b[j]; }
    *(bf16x8*)(dst + 8 * (size_t)i) = o;
}

// ---------------------------------------------------------------- GEMM (NT)
// C[i][j] = sum_k A[i*K+k] * B[j*K+k].  128x128 tile, BK=64, dbuf LDS,
// one barrier per K-step (stage t+1 || compute t).  LDS XOR-swizzled:
// LDS[row][chunk] = G[row][chunk ^ (row&7)]  (16B chunks, 8 per 128B row)
// so ds_read_b128 across 16 rows is 2-way (free) instead of 16-way.
// EPI=1: bias+ELU -> bf16   EPI=2: bias -> f32 (d_out) + bf16 copy
// EPI=3: e=exp2(acc*rn0*rn1*C); row partial sums of e, e*pos -> pS/pP
template <int EPI>
__global__ __launch_bounds__(256, 2)
void gemm_bt(const bf16_t* __restrict__ A, const bf16_t* __restrict__ B, int K,
             const float* __restrict__ bias,
             bf16_t* __restrict__ outb, float* __restrict__ outf,
             const float* __restrict__ rn0, const float* __restrict__ rn1,
             const float* __restrict__ pos,
             float* __restrict__ pS, float* __restrict__ pP) {
    __shared__ __align__(16) bf16_t As[2][128 * 64];
    __shared__ __align__(16) bf16_t Bs[2][128 * 64];

    const int tid  = threadIdx.x;
    const int lane = tid & 63;
    const int wv   = tid >> 6;   // 0..3
    const int wm   = wv >> 1;    // wave row
    const int wn   = wv & 1;     // wave col

    long ibase, jbase;
    int  jt = 0;
    if constexpr (EPI == 3) {
        // bijective XCD swizzle (4096 blocks % 8 == 0): XCD x owns j-panels [8x,8x+8)
        const int flat = blockIdx.y * 64 + blockIdx.x;
        const int swz  = (flat & 7) * 512 + (flat >> 3);
        ibase = (long)(swz & 63) * 128;
        jt    = swz >> 6;
        jbase = (long)jt * 128;
    } else {
        ibase = (long)blockIdx.x * 128;
        jbase = (long)blockIdx.y * 128;
    }

    const int r8  = lane >> 3;   // row within 8-row staging chunk
    const int c16 = lane & 7;    // 16B chunk within 128B row

    auto STAGE = [&](int buf, int t) {
        const int k0 = t * 64;
#pragma unroll
        for (int s = 0; s < 4; ++s) {
            const int row = wv * 32 + s * 8 + r8;
            const int ce  = (c16 ^ (row & 7)) << 3;  // swizzled elem offset
            __builtin_amdgcn_global_load_lds(AS1(A + (ibase + row) * (long)K + k0 + ce),
                                             AS3(&As[buf][(wv * 32 + s * 8) * 64]), 16, 0, 0);
            __builtin_amdgcn_global_load_lds(AS1(B + (jbase + row) * (long)K + k0 + ce),
                                             AS3(&Bs[buf][(wv * 32 + s * 8) * 64]), 16, 0, 0);
        }
    };

    f32x4 acc[4][4] = {};
    const int fr = lane & 15;   // fragment row within 16
    const int fj = lane >> 4;   // 16B chunk index within 64B k-half
    const int NT = K >> 6;      // 8

    STAGE(0, 0);
    __syncthreads();            // vmcnt(0) drain + barrier
    int cur = 0;
    for (int t = 0; t < NT; ++t) {
        if (t + 1 < NT) STAGE(cur ^ 1, t + 1);  // overlaps with compute of t
        bf16x8 af[2][4], bfr[2][4];
#pragma unroll
        for (int kk = 0; kk < 2; ++kk) {
#pragma unroll
            for (int m = 0; m < 4; ++m) {
                const int row = wm * 64 + m * 16 + fr;
                af[kk][m] = *(const bf16x8*)((const char*)&As[cur][0] + row * 128 +
                                             (((kk * 4 + fj) ^ (fr & 7)) << 4));
            }
#pragma unroll
            for (int n = 0; n < 4; ++n) {
                const int row = wn * 64 + n * 16 + fr;
                bfr[kk][n] = *(const bf16x8*)((const char*)&Bs[cur][0] + row * 128 +
                                              (((kk * 4 + fj) ^ (fr & 7)) << 4));
            }
        }
#pragma unroll
        for (int kk = 0; kk < 2; ++kk)
#pragma unroll
            for (int m = 0; m < 4; ++m)
#pragma unroll
                for (int n = 0; n < 4; ++n)
                    acc[m][n] = __builtin_amdgcn_mfma_f32_16x16x32_bf16(af[kk][m], bfr[kk][n],
                                                                        acc[m][n], 0, 0, 0);
        __syncthreads();        // reads of cur done; stage of cur^1 drained
        cur ^= 1;
    }

    // D mapping (m89): col = lane&15, row = (lane>>4)*4 + reg
    const int crow = fj << 2;
    const int ccol = fr;

    if constexpr (EPI == 1 || EPI == 2) {
#pragma unroll
        for (int m = 0; m < 4; ++m) {
            const long rowb = ibase + wm * 64 + m * 16 + crow;
#pragma unroll
            for (int n = 0; n < 4; ++n) {
                const int col = (int)jbase + wn * 64 + n * 16 + ccol;
                const float bv = bias[col];
#pragma unroll
                for (int r = 0; r < 4; ++r) {
                    float v = acc[m][n][r] + bv;
                    const long idx = (rowb + r) * HDIM + col;
                    if constexpr (EPI == 1) {
                        v = v > 0.f ? v : expm1f(v);  // ELU(alpha=1)
                        outb[idx] = (bf16_t)v;
                    } else {
                        outf[idx] = v;
                        outb[idx] = (bf16_t)v;
                    }
                }
            }
        }
    } else {
        // reuse the 64KB A/B LDS (K-loop done, last barrier passed) as f32 scratch:
        // sS/sP [4 waves][64 rows][20 pad]  (stride 20 keeps 16B align, ~2-way banks)
        float* sS = (float*)&As[0][0];
        float* sP = (float*)&Bs[0][0];
        float r1v[4];
#pragma unroll
        for (int n = 0; n < 4; ++n) r1v[n] = rn1[jbase + wn * 64 + n * 16 + ccol] * C_EXP2;
#pragma unroll
        for (int m = 0; m < 4; ++m) {
#pragma unroll
            for (int r = 0; r < 4; ++r) {
                const int roww  = m * 16 + crow + r;          // 0..63 within wave
                const long grow = ibase + wm * 64 + roww;
                const float r0  = rn0[grow];
                const float* prow = pos + grow * (long)NROWS + jbase + wn * 64 + ccol;
                float eS = 0.f, eP = 0.f;
#pragma unroll
                for (int n = 0; n < 4; ++n) {
                    const float e = exp2f(acc[m][n][r] * r0 * r1v[n]);
                    eS += e;
                    eP += e * prow[n * 16];
                }
                sS[(wv * 64 + roww) * 20 + ccol] = eS;
                sP[(wv * 64 + roww) * 20 + ccol] = eP;
            }
        }
        __syncthreads();
        if (tid < 128) {
            const int rr  = tid;          // row within 128-tile
            const int wmr = rr >> 6;
            const int rw  = rr & 63;
            float S = 0.f, P = 0.f;
#pragma unroll
            for (int h = 0; h < 2; ++h) {
                const float* bS = &sS[((wmr * 2 + h) * 64 + rw) * 20];
                const float* bP = &sP[((wmr * 2 + h) * 64 + rw) * 20];
#pragma unroll
                for (int c = 0; c < 16; c += 4) {
                    f32x4 v = *(const f32x4*)(bS + c);
                    f32x4 w = *(const f32x4*)(bP + c);
                    S += v[0] + v[1] + v[2] + v[3];
                    P += w[0] + w[1] + w[2] + w[3];
                }
            }
            pS[(long)jt * NROWS + ibase + rr] = S;
            pP[(long)jt * NROWS + ibase + rr] = P;
        }
    }
}

// ---------------------------------------------------------------- row norms
__global__ __launch_bounds__(256) void rownorm(const bf16_t* __restrict__ Z,
                                               float* __restrict__ rn) {
    const int row  = blockIdx.x * 4 + (threadIdx.x >> 6);
    const int lane = threadIdx.x & 63;
    bf16x8 v = *(const bf16x8*)&Z[(size_t)row * HDIM + lane * 8];
    float s = 0.f;
#pragma unroll
    for (int j = 0; j < 8; ++j) { float f = (float)v[j]; s += f * f; }
#pragma unroll
    for (int off = 32; off > 0; off >>= 1) s += __shfl_xor(s, off);
    if (lane == 0) rn[row] = rsqrtf(s);
}

// ---------------------------------------------------------------- reductions
__global__ __launch_bounds__(256) void reduce_rows(const float* __restrict__ pS,
                                                   const float* __restrict__ pP,
                                                   float* __restrict__ bsum) {
    const int i = blockIdx.x * 256 + threadIdx.x;  // row 0..8191
    float S = 0.f, P = 0.f;
    for (int jb = 0; jb < 64; ++jb) {
        S += pS[jb * NROWS + i];
        P += pP[jb * NROWS + i];
    }
    float t = logf(P / (S + 1e-8f) + 1e-8f);
#pragma unroll
    for (int off = 32; off > 0; off >>= 1) t += __shfl_xor(t, off);
    __shared__ float red[4];
    if ((threadIdx.x & 63) == 0) red[threadIdx.x >> 6] = t;
    __syncthreads();
    if (threadIdx.x == 0) bsum[blockIdx.x] = red[0] + red[1] + red[2] + red[3];
}

__global__ void finalize(const float* __restrict__ bsum, float* __restrict__ loss) {
    float t = (threadIdx.x < 32) ? bsum[threadIdx.x] : 0.f;
#pragma unroll
    for (int off = 32; off > 0; off >>= 1) t += __shfl_xor(t, off);
    if (threadIdx.x == 0) *loss = -(t * (1.0f / 8192.0f));
}

// ---------------------------------------------------------------- launch
extern "C" void kernel_launch(void* const* d_in, const int* in_sizes, int n_in,
                              void* d_out, int out_size, void* d_ws, size_t ws_size,
                              hipStream_t stream) {
    const float* embd0 = (const float*)d_in[0];
    const float* embd1 = (const float*)d_in[1];
    const float* pos   = (const float*)d_in[2];
    const float* W1    = (const float*)d_in[3];
    const float* b1    = (const float*)d_in[4];
    const float* W2    = (const float*)d_in[5];
    const float* b2    = (const float*)d_in[6];
    float* out = (float*)d_out;  // [z0 | z1 | loss]

    char* ws = (char*)d_ws;
    bf16_t* Xb   = (bf16_t*)(ws);               // 16 MB  [16384][512]
    bf16_t* Hb   = (bf16_t*)(ws + 16777216);    // 16 MB
    bf16_t* Zb   = (bf16_t*)(ws + 33554432);    // 16 MB
    bf16_t* W1b  = (bf16_t*)(ws + 50331648);    // 512 KB
    bf16_t* W2b  = (bf16_t*)(ws + 50855936);    // 512 KB
    float*  rn   = (float*)(ws + 51380224);     // 64 KB (rn0|rn1)
    float*  pS   = (float*)(ws + 51445760);     // 2 MB [64][8192]
    float*  pP   = (float*)(ws + 53542912);     // 2 MB
    float*  bsum = (float*)(ws + 55640064);     // 128 B

    cvt_f32_bf16<<<2048, 256, 0, stream>>>(embd0, Xb, 524288);
    cvt_f32_bf16<<<2048, 256, 0, stream>>>(embd1, Xb + 4194304, 524288);
    cvt_f32_bf16<<<128, 256, 0, stream>>>(W1, W1b, 32768);
    cvt_f32_bf16<<<128, 256, 0, stream>>>(W2, W2b, 32768);

    gemm_bt<1><<<dim3(128, 4), 256, 0, stream>>>(Xb, W1b, HDIM, b1, Hb, nullptr,
                                                 nullptr, nullptr, nullptr, nullptr, nullptr);
    gemm_bt<2><<<dim3(128, 4), 256, 0, stream>>>(Hb, W2b, HDIM, b2, Zb, out,
                                                 nullptr, nullptr, nullptr, nullptr, nullptr);
    rownorm<<<4096, 256, 0, stream>>>(Zb, rn);
    gemm_bt<3><<<dim3(64, 64), 256, 0, stream>>>(Zb, Zb + 4194304, HDIM, nullptr,
                                                 nullptr, nullptr, rn, rn + NROWS, pos,
                                                 pS, pP);
    reduce_rows<<<32, 256, 0, stream>>>(pS, pP, bsum);
    finalize<<<1, 64, 0, stream>>>(bsum, out + 8388608);
}

// Round 3
// 204.782 us; speedup vs baseline: 1.1838x; 1.0461x over previous
//
#include <hip/hip_runtime.h>
#include <hip/hip_bf16.h>
#include <cmath>

typedef __bf16 bf16_t;
typedef __bf16 bf16x8 __attribute__((ext_vector_type(8)));
typedef float  f32x4  __attribute__((ext_vector_type(4)));

#define AS1(p) ((__attribute__((address_space(1))) void*)(p))
#define AS3(p) ((__attribute__((address_space(3))) void*)(p))

// N=8192, H=512, TAU=0.5, EPS=1e-8
// exp(x) = exp2(x * log2e / TAU); (1/0.5)*log2e = 2.885390...
#define C_EXP2 2.8853900817779268f
#define NROWS  8192
#define HDIM   512

// ---------------------------------------------------------------- f32->bf16
__global__ __launch_bounds__(256) void cvt_f32_bf16(const float* __restrict__ src,
                                                    bf16_t* __restrict__ dst, int n8) {
    int i = blockIdx.x * 256 + threadIdx.x;
    if (i >= n8) return;
    const f32x4* s4 = (const f32x4*)src;
    f32x4 a = s4[2 * (size_t)i];
    f32x4 b = s4[2 * (size_t)i + 1];
    bf16x8 o;
#pragma unroll
    for (int j = 0; j < 4; ++j) { o[j] = (bf16_t)a[j]; o[4 + j] = (bf16_t)b[j]; }
    *(bf16x8*)(dst + 8 * (size_t)i) = o;
}

// ---------------------------------------------------------------- GEMM (NT)
// C[i][j] = sum_k A[i*K+k] * B[j*K+k].  128x128 tile, BK=64, dbuf LDS,
// one barrier per K-step.  LDS XOR-swizzled (16B chunks, chunk ^= row&7):
// ds_read_b128 across 16 rows is 2-way (free).
// EPI=1: bias+ELU -> bf16   EPI=2: bias -> f32 (d_out) + bf16 copy
// EPI=3: pos/rn prefetched to regs BEFORE K-loop (T14 issue-early);
//        e=exp2(acc*rn0*rn1*C); row partial sums of e, e*pos -> pS/pP
template <int EPI>
__global__ __launch_bounds__(256, 2)
void gemm_bt(const bf16_t* __restrict__ A, const bf16_t* __restrict__ B, int K,
             const float* __restrict__ bias,
             bf16_t* __restrict__ outb, float* __restrict__ outf,
             const float* __restrict__ rn0, const float* __restrict__ rn1,
             const float* __restrict__ pos,
             float* __restrict__ pS, float* __restrict__ pP) {
    __shared__ __align__(16) bf16_t As[2][128 * 64];
    __shared__ __align__(16) bf16_t Bs[2][128 * 64];

    const int tid  = threadIdx.x;
    const int lane = tid & 63;
    const int wv   = tid >> 6;   // 0..3
    const int wm   = wv >> 1;    // wave row
    const int wn   = wv & 1;     // wave col

    long ibase, jbase;
    int  jt = 0;
    if constexpr (EPI == 3) {
        // bijective XCD swizzle (4096 blocks, %8==0): XCD x owns j-panels [8x,8x+8)
        const int flat = blockIdx.y * 64 + blockIdx.x;
        const int swz  = (flat & 7) * 512 + (flat >> 3);
        ibase = (long)(swz & 63) * 128;
        jt    = swz >> 6;
        jbase = (long)jt * 128;
    } else {
        ibase = (long)blockIdx.x * 128;
        jbase = (long)blockIdx.y * 128;
    }

    const int r8  = lane >> 3;   // row within 8-row staging chunk
    const int c16 = lane & 7;    // 16B chunk within 128B row

    auto STAGE = [&](int buf, int t) {
        const int k0 = t * 64;
#pragma unroll
        for (int s = 0; s < 4; ++s) {
            const int row = wv * 32 + s * 8 + r8;
            const int ce  = (c16 ^ (row & 7)) << 3;  // swizzled elem offset
            __builtin_amdgcn_global_load_lds(AS1(A + (ibase + row) * (long)K + k0 + ce),
                                             AS3(&As[buf][(wv * 32 + s * 8) * 64]), 16, 0, 0);
            __builtin_amdgcn_global_load_lds(AS1(B + (jbase + row) * (long)K + k0 + ce),
                                             AS3(&Bs[buf][(wv * 32 + s * 8) * 64]), 16, 0, 0);
        }
    };

    f32x4 acc[4][4] = {};
    const int fr = lane & 15;   // fragment row within 16 (C col)
    const int fj = lane >> 4;   // 16B chunk index (C row group)
    const int NT = K >> 6;      // 8
    const int crow = fj << 2;
    const int ccol = fr;

    // ---- issue staging for t=0, then pos/rn prefetch (T14 issue-early) ----
    STAGE(0, 0);

    float pf[16][4];   // pos tile, fragment layout: [m*4+r][n]
    float r0v[16];     // rn0 * C_EXP2 per fragment row
    float r1v[4];      // rn1 per fragment col
    if constexpr (EPI == 3) {
#pragma unroll
        for (int n = 0; n < 4; ++n) r1v[n] = rn1[jbase + wn * 64 + n * 16 + ccol];
#pragma unroll
        for (int mr = 0; mr < 16; ++mr) {
            const int m = mr >> 2, r = mr & 3;
            const long grow = ibase + wm * 64 + m * 16 + crow + r;
            const float* prow = pos + grow * (long)NROWS + jbase + wn * 64 + ccol;
#pragma unroll
            for (int n = 0; n < 4; ++n) pf[mr][n] = prow[n * 16];
            r0v[mr] = rn0[grow] * C_EXP2;
        }
    }

    __syncthreads();            // drains stage(0) + prefetch burst
    int cur = 0;
    for (int t = 0; t < NT; ++t) {
        if (t + 1 < NT) STAGE(cur ^ 1, t + 1);  // lands under compute of t
#pragma unroll
        for (int kk = 0; kk < 2; ++kk) {
            bf16x8 af[4], bfr[4];
#pragma unroll
            for (int m = 0; m < 4; ++m) {
                const int row = wm * 64 + m * 16 + fr;
                af[m] = *(const bf16x8*)((const char*)&As[cur][0] + row * 128 +
                                         (((kk * 4 + fj) ^ (fr & 7)) << 4));
            }
#pragma unroll
            for (int n = 0; n < 4; ++n) {
                const int row = wn * 64 + n * 16 + fr;
                bfr[n] = *(const bf16x8*)((const char*)&Bs[cur][0] + row * 128 +
                                          (((kk * 4 + fj) ^ (fr & 7)) << 4));
            }
#pragma unroll
            for (int m = 0; m < 4; ++m)
#pragma unroll
                for (int n = 0; n < 4; ++n)
                    acc[m][n] = __builtin_amdgcn_mfma_f32_16x16x32_bf16(af[m], bfr[n],
                                                                        acc[m][n], 0, 0, 0);
        }
        __syncthreads();        // reads of cur done; stage of cur^1 drained
        cur ^= 1;
    }

    if constexpr (EPI == 1 || EPI == 2) {
#pragma unroll
        for (int m = 0; m < 4; ++m) {
            const long rowb = ibase + wm * 64 + m * 16 + crow;
#pragma unroll
            for (int n = 0; n < 4; ++n) {
                const int col = (int)jbase + wn * 64 + n * 16 + ccol;
                const float bv = bias[col];
#pragma unroll
                for (int r = 0; r < 4; ++r) {
                    float v = acc[m][n][r] + bv;
                    const long idx = (rowb + r) * HDIM + col;
                    if constexpr (EPI == 1) {
                        v = v > 0.f ? v : expm1f(v);  // ELU(alpha=1)
                        outb[idx] = (bf16_t)v;
                    } else {
                        outf[idx] = v;
                        outb[idx] = (bf16_t)v;
                    }
                }
            }
        }
    } else {
        // epilogue: pure VALU (exp2) + LDS reduce — no global loads
        // reuse the 64KB A/B LDS as f32 scratch [4 waves][64 rows][stride 20]
        float* sS = (float*)&As[0][0];
        float* sP = (float*)&Bs[0][0];
#pragma unroll
        for (int mr = 0; mr < 16; ++mr) {
            const int m = mr >> 2, r = mr & 3;
            const int roww = m * 16 + crow + r;          // 0..63 within wave
            float eS = 0.f, eP = 0.f;
#pragma unroll
            for (int n = 0; n < 4; ++n) {
                const float e = exp2f(acc[m][n][r] * r0v[mr] * r1v[n]);
                eS += e;
                eP += e * pf[mr][n];
            }
            sS[(wv * 64 + roww) * 20 + ccol] = eS;
            sP[(wv * 64 + roww) * 20 + ccol] = eP;
        }
        __syncthreads();
        if (tid < 128) {
            const int rr  = tid;          // row within 128-tile
            const int wmr = rr >> 6;
            const int rw  = rr & 63;
            float S = 0.f, P = 0.f;
#pragma unroll
            for (int h = 0; h < 2; ++h) {
                const float* bS = &sS[((wmr * 2 + h) * 64 + rw) * 20];
                const float* bP = &sP[((wmr * 2 + h) * 64 + rw) * 20];
#pragma unroll
                for (int c = 0; c < 16; c += 4) {
                    f32x4 v = *(const f32x4*)(bS + c);
                    f32x4 w = *(const f32x4*)(bP + c);
                    S += v[0] + v[1] + v[2] + v[3];
                    P += w[0] + w[1] + w[2] + w[3];
                }
            }
            pS[(long)jt * NROWS + ibase + rr] = S;
            pP[(long)jt * NROWS + ibase + rr] = P;
        }
    }
}

// ---------------------------------------------------------------- row norms
__global__ __launch_bounds__(256) void rownorm(const bf16_t* __restrict__ Z,
                                               float* __restrict__ rn) {
    const int row  = blockIdx.x * 4 + (threadIdx.x >> 6);
    const int lane = threadIdx.x & 63;
    bf16x8 v = *(const bf16x8*)&Z[(size_t)row * HDIM + lane * 8];
    float s = 0.f;
#pragma unroll
    for (int j = 0; j < 8; ++j) { float f = (float)v[j]; s += f * f; }
#pragma unroll
    for (int off = 32; off > 0; off >>= 1) s += __shfl_xor(s, off);
    if (lane == 0) rn[row] = rsqrtf(s);
}

// ---------------------------------------------------------------- reductions
__global__ __launch_bounds__(256) void reduce_rows(const float* __restrict__ pS,
                                                   const float* __restrict__ pP,
                                                   float* __restrict__ bsum) {
    const int i = blockIdx.x * 256 + threadIdx.x;  // row 0..8191
    float S = 0.f, P = 0.f;
    for (int jb = 0; jb < 64; ++jb) {
        S += pS[jb * NROWS + i];
        P += pP[jb * NROWS + i];
    }
    float t = logf(P / (S + 1e-8f) + 1e-8f);
#pragma unroll
    for (int off = 32; off > 0; off >>= 1) t += __shfl_xor(t, off);
    __shared__ float red[4];
    if ((threadIdx.x & 63) == 0) red[threadIdx.x >> 6] = t;
    __syncthreads();
    if (threadIdx.x == 0) bsum[blockIdx.x] = red[0] + red[1] + red[2] + red[3];
}

__global__ void finalize(const float* __restrict__ bsum, float* __restrict__ loss) {
    float t = (threadIdx.x < 32) ? bsum[threadIdx.x] : 0.f;
#pragma unroll
    for (int off = 32; off > 0; off >>= 1) t += __shfl_xor(t, off);
    if (threadIdx.x == 0) *loss = -(t * (1.0f / 8192.0f));
}

// ---------------------------------------------------------------- launch
extern "C" void kernel_launch(void* const* d_in, const int* in_sizes, int n_in,
                              void* d_out, int out_size, void* d_ws, size_t ws_size,
                              hipStream_t stream) {
    const float* embd0 = (const float*)d_in[0];
    const float* embd1 = (const float*)d_in[1];
    const float* pos   = (const float*)d_in[2];
    const float* W1    = (const float*)d_in[3];
    const float* b1    = (const float*)d_in[4];
    const float* W2    = (const float*)d_in[5];
    const float* b2    = (const float*)d_in[6];
    float* out = (float*)d_out;  // [z0 | z1 | loss]

    char* ws = (char*)d_ws;
    bf16_t* Xb   = (bf16_t*)(ws);               // 16 MB  [16384][512]
    bf16_t* Hb   = (bf16_t*)(ws + 16777216);    // 16 MB
    bf16_t* Zb   = (bf16_t*)(ws + 33554432);    // 16 MB
    bf16_t* W1b  = (bf16_t*)(ws + 50331648);    // 512 KB
    bf16_t* W2b  = (bf16_t*)(ws + 50855936);    // 512 KB
    float*  rn   = (float*)(ws + 51380224);     // 64 KB (rn0|rn1)
    float*  pS   = (float*)(ws + 51445760);     // 2 MB [64][8192]
    float*  pP   = (float*)(ws + 53542912);     // 2 MB
    float*  bsum = (float*)(ws + 55640064);     // 128 B

    cvt_f32_bf16<<<2048, 256, 0, stream>>>(embd0, Xb, 524288);
    cvt_f32_bf16<<<2048, 256, 0, stream>>>(embd1, Xb + 4194304, 524288);
    cvt_f32_bf16<<<128, 256, 0, stream>>>(W1, W1b, 32768);
    cvt_f32_bf16<<<128, 256, 0, stream>>>(W2, W2b, 32768);

    gemm_bt<1><<<dim3(128, 4), 256, 0, stream>>>(Xb, W1b, HDIM, b1, Hb, nullptr,
                                                 nullptr, nullptr, nullptr, nullptr, nullptr);
    gemm_bt<2><<<dim3(128, 4), 256, 0, stream>>>(Hb, W2b, HDIM, b2, Zb, out,
                                                 nullptr, nullptr, nullptr, nullptr, nullptr);
    rownorm<<<4096, 256, 0, stream>>>(Zb, rn);
    gemm_bt<3><<<dim3(64, 64), 256, 0, stream>>>(Zb, Zb + 4194304, HDIM, nullptr,
                                                 nullptr, nullptr, rn, rn + NROWS, pos,
                                                 pS, pP);
    reduce_rows<<<32, 256, 0, stream>>>(pS, pP, bsum);
    finalize<<<1, 64, 0, stream>>>(bsum, out + 8388608);
}

// Round 4
// 191.755 us; speedup vs baseline: 1.2642x; 1.0679x over previous
//
#include <hip/hip_runtime.h>
#include <hip/hip_bf16.h>
#include <cmath>

typedef __bf16 bf16_t;
typedef __bf16 bf16x8 __attribute__((ext_vector_type(8)));
typedef float  f32x4  __attribute__((ext_vector_type(4)));

#define AS1(p) ((__attribute__((address_space(1))) void*)(p))
#define AS3(p) ((__attribute__((address_space(3))) void*)(p))

// N=8192, H=512, TAU=0.5, EPS=1e-8
// exp(x) = exp2(x * log2e / TAU); (1/0.5)*log2e = 2.885390...
#define C_EXP2 2.8853900817779268f
#define NROWS  8192
#define HDIM   512

// ---------------------------------------------------------------- f32->bf16
__global__ __launch_bounds__(256) void cvt_f32_bf16(const float* __restrict__ src,
                                                    bf16_t* __restrict__ dst, int n8) {
    int i = blockIdx.x * 256 + threadIdx.x;
    if (i >= n8) return;
    const f32x4* s4 = (const f32x4*)src;
    f32x4 a = s4[2 * (size_t)i];
    f32x4 b = s4[2 * (size_t)i + 1];
    bf16x8 o;
#pragma unroll
    for (int j = 0; j < 4; ++j) { o[j] = (bf16_t)a[j]; o[4 + j] = (bf16_t)b[j]; }
    *(bf16x8*)(dst + 8 * (size_t)i) = o;
}

// ---------------------------------------------------------------- GEMM (NT)
// C[i][j] = sum_k A[i*K+k] * B[j*K+k], K=512. 128x128 tile, BK=64, 2-deep dbuf,
// fully-unrolled 8-step pipeline with RAW s_barrier + COUNTED vmcnt (T4):
//   step t: issue stage(t+1) | issue 8 pos loads (EPI3) | ds_read+MFMA buf t&1
//           | s_waitcnt vmcnt(8) (stage(t+1) drained, pos stays in flight)
//           | s_barrier
// LDS XOR-swizzled (16B chunks, chunk ^= row&7): ds_read_b128 2-way (free).
// EPI=1: bias+ELU -> bf16   EPI=2: bias -> f32 (d_out) + bf16 copy
// EPI=3: e=exp2(acc*rn0*rn1*C); row partial sums of e, e*pos -> pS/pP
template <int EPI>
__global__ __launch_bounds__(256, 2)
void gemm_bt(const bf16_t* __restrict__ A, const bf16_t* __restrict__ B,
             const float* __restrict__ bias,
             bf16_t* __restrict__ outb, float* __restrict__ outf,
             const float* __restrict__ rn0, const float* __restrict__ rn1,
             const float* __restrict__ pos,
             float* __restrict__ pS, float* __restrict__ pP) {
    constexpr int K  = 512;
    constexpr int NT = 8;
    __shared__ __align__(16) bf16_t As[2][128 * 64];
    __shared__ __align__(16) bf16_t Bs[2][128 * 64];

    const int tid  = threadIdx.x;
    const int lane = tid & 63;
    const int wv   = tid >> 6;   // 0..3
    const int wm   = wv >> 1;    // wave row
    const int wn   = wv & 1;     // wave col

    long ibase, jbase;
    int  jt = 0;
    if constexpr (EPI == 3) {
        // bijective XCD swizzle (4096 blocks, %8==0): XCD x owns j-panels [8x,8x+8)
        const int flat = blockIdx.y * 64 + blockIdx.x;
        const int swz  = (flat & 7) * 512 + (flat >> 3);
        ibase = (long)(swz & 63) * 128;
        jt    = swz >> 6;
        jbase = (long)jt * 128;
    } else {
        ibase = (long)blockIdx.x * 128;
        jbase = (long)blockIdx.y * 128;
    }

    const int r8  = lane >> 3;   // row within 8-row staging chunk
    const int c16 = lane & 7;    // 16B chunk within 128B row
    // staging: per-thread global base (swizzle col fold: (c16^r8)*8, t-invariant)
    const long aSrc0 = (ibase + wv * 32 + r8) * (long)K + ((c16 ^ r8) << 3);
    const long bSrc0 = (jbase + wv * 32 + r8) * (long)K + ((c16 ^ r8) << 3);

    f32x4 acc[4][4] = {};
    const int fr = lane & 15;   // fragment row within 16 (C col)
    const int fj = lane >> 4;   // 16B chunk index (C row group)
    const int crow = fj << 2;
    const int ccol = fr;

    float pf[16][4];   // pos tile, fragment layout [m*4+r][n]
    float r0v[16];     // rn0 * C_EXP2 per fragment row
    float r1v[4];      // rn1 per fragment col
    const float* posRowBase = nullptr;
    if constexpr (EPI == 3)
        posRowBase = pos + (size_t)(ibase + wm * 64 + crow) * NROWS + jbase + wn * 64 + ccol;

    // ---------------- prologue: stage(0) first (oldest in vmcnt queue), then rn
    {
#pragma unroll
        for (int s = 0; s < 4; ++s) {
            __builtin_amdgcn_global_load_lds(AS1(A + aSrc0 + s * 8 * K),
                                             AS3(&As[0][(wv * 32 + s * 8) * 64]), 16, 0, 0);
            __builtin_amdgcn_global_load_lds(AS1(B + bSrc0 + s * 8 * K),
                                             AS3(&Bs[0][(wv * 32 + s * 8) * 64]), 16, 0, 0);
        }
    }
    if constexpr (EPI == 3) {
        asm volatile("" ::: "memory");  // rn loads stay AFTER stage(0) in queue
#pragma unroll
        for (int n = 0; n < 4; ++n) r1v[n] = rn1[jbase + wn * 64 + n * 16 + ccol];
#pragma unroll
        for (int mr = 0; mr < 16; ++mr)
            r0v[mr] = rn0[ibase + wm * 64 + (mr >> 2) * 16 + crow + (mr & 3)] * C_EXP2;
        asm volatile("s_waitcnt vmcnt(20)" ::: "memory");  // stage(0) landed, rn in flight
    } else {
        asm volatile("s_waitcnt vmcnt(0)" ::: "memory");
    }
    __builtin_amdgcn_s_barrier();
    asm volatile("" ::: "memory");

    // ---------------- pipelined K-loop (fully unrolled, compile-time t)
#pragma unroll
    for (int t = 0; t < NT; ++t) {
        if (t + 1 < NT) {
            const int nb = (t + 1) & 1;
#pragma unroll
            for (int s = 0; s < 4; ++s) {
                __builtin_amdgcn_global_load_lds(AS1(A + aSrc0 + s * 8 * K + (t + 1) * 64),
                                                 AS3(&As[nb][(wv * 32 + s * 8) * 64]), 16, 0, 0);
                __builtin_amdgcn_global_load_lds(AS1(B + bSrc0 + s * 8 * K + (t + 1) * 64),
                                                 AS3(&Bs[nb][(wv * 32 + s * 8) * 64]), 16, 0, 0);
            }
        }
        asm volatile("" ::: "memory");  // pin: pos loads issue AFTER stage(t+1)
        if constexpr (EPI == 3) {
#pragma unroll
            for (int h = 0; h < 2; ++h) {
                const int mr = 2 * t + h;
                const float* prow = posRowBase + ((mr >> 2) * 16 + (mr & 3)) * (size_t)NROWS;
#pragma unroll
                for (int n = 0; n < 4; ++n)
                    pf[mr][n] = __builtin_nontemporal_load(prow + n * 16);
            }
        }
        // compute on buf t&1
#pragma unroll
        for (int kk = 0; kk < 2; ++kk) {
            bf16x8 af[4], bfr[4];
#pragma unroll
            for (int m = 0; m < 4; ++m) {
                const int row = wm * 64 + m * 16 + fr;
                af[m] = *(const bf16x8*)((const char*)&As[t & 1][0] + row * 128 +
                                         (((kk * 4 + fj) ^ (fr & 7)) << 4));
            }
#pragma unroll
            for (int n = 0; n < 4; ++n) {
                const int row = wn * 64 + n * 16 + fr;
                bfr[n] = *(const bf16x8*)((const char*)&Bs[t & 1][0] + row * 128 +
                                          (((kk * 4 + fj) ^ (fr & 7)) << 4));
            }
            __builtin_amdgcn_s_setprio(1);
#pragma unroll
            for (int m = 0; m < 4; ++m)
#pragma unroll
                for (int n = 0; n < 4; ++n)
                    acc[m][n] = __builtin_amdgcn_mfma_f32_16x16x32_bf16(af[m], bfr[n],
                                                                        acc[m][n], 0, 0, 0);
            __builtin_amdgcn_s_setprio(0);
        }
        asm volatile("" ::: "memory");
        if (t + 1 < NT) {
            // counted: stage(t+1) drained; pos loads stay in flight across barrier
            if constexpr (EPI == 3) asm volatile("s_waitcnt vmcnt(8)" ::: "memory");
            else                    asm volatile("s_waitcnt vmcnt(0)" ::: "memory");
        }
        __builtin_amdgcn_s_barrier();
        asm volatile("" ::: "memory");
    }

    if constexpr (EPI == 1 || EPI == 2) {
#pragma unroll
        for (int m = 0; m < 4; ++m) {
            const long rowb = ibase + wm * 64 + m * 16 + crow;
#pragma unroll
            for (int n = 0; n < 4; ++n) {
                const int col = (int)jbase + wn * 64 + n * 16 + ccol;
                const float bv = bias[col];
#pragma unroll
                for (int r = 0; r < 4; ++r) {
                    float v = acc[m][n][r] + bv;
                    const long idx = (rowb + r) * HDIM + col;
                    if constexpr (EPI == 1) {
                        v = v > 0.f ? v : expm1f(v);  // ELU(alpha=1)
                        outb[idx] = (bf16_t)v;
                    } else {
                        outf[idx] = v;
                        outb[idx] = (bf16_t)v;
                    }
                }
            }
        }
    } else {
        // epilogue: pure VALU (exp2) + LDS reduce; pf/r0v/r1v waited by compiler
        float* sS = (float*)&As[0][0];
        float* sP = (float*)&Bs[0][0];
#pragma unroll
        for (int mr = 0; mr < 16; ++mr) {
            const int m = mr >> 2, r = mr & 3;
            const int roww = m * 16 + crow + r;          // 0..63 within wave
            float eS = 0.f, eP = 0.f;
#pragma unroll
            for (int n = 0; n < 4; ++n) {
                const float e = exp2f(acc[m][n][r] * r0v[mr] * r1v[n]);
                eS += e;
                eP += e * pf[mr][n];
            }
            sS[(wv * 64 + roww) * 20 + ccol] = eS;
            sP[(wv * 64 + roww) * 20 + ccol] = eP;
        }
        __syncthreads();
        if (tid < 128) {
            const int rr  = tid;          // row within 128-tile
            const int wmr = rr >> 6;
            const int rw  = rr & 63;
            float S = 0.f, P = 0.f;
#pragma unroll
            for (int h = 0; h < 2; ++h) {
                const float* bS = &sS[((wmr * 2 + h) * 64 + rw) * 20];
                const float* bP = &sP[((wmr * 2 + h) * 64 + rw) * 20];
#pragma unroll
                for (int c = 0; c < 16; c += 4) {
                    f32x4 v = *(const f32x4*)(bS + c);
                    f32x4 w = *(const f32x4*)(bP + c);
                    S += v[0] + v[1] + v[2] + v[3];
                    P += w[0] + w[1] + w[2] + w[3];
                }
            }
            pS[(long)jt * NROWS + ibase + rr] = S;
            pP[(long)jt * NROWS + ibase + rr] = P;
        }
    }
}

// ---------------------------------------------------------------- row norms
__global__ __launch_bounds__(256) void rownorm(const bf16_t* __restrict__ Z,
                                               float* __restrict__ rn) {
    const int row  = blockIdx.x * 4 + (threadIdx.x >> 6);
    const int lane = threadIdx.x & 63;
    bf16x8 v = *(const bf16x8*)&Z[(size_t)row * HDIM + lane * 8];
    float s = 0.f;
#pragma unroll
    for (int j = 0; j < 8; ++j) { float f = (float)v[j]; s += f * f; }
#pragma unroll
    for (int off = 32; off > 0; off >>= 1) s += __shfl_xor(s, off);
    if (lane == 0) rn[row] = rsqrtf(s);
}

// ---------------------------------------------------------------- reductions
__global__ __launch_bounds__(256) void reduce_rows(const float* __restrict__ pS,
                                                   const float* __restrict__ pP,
                                                   float* __restrict__ bsum) {
    const int i = blockIdx.x * 256 + threadIdx.x;  // row 0..8191
    float S = 0.f, P = 0.f;
    for (int jb = 0; jb < 64; ++jb) {
        S += pS[jb * NROWS + i];
        P += pP[jb * NROWS + i];
    }
    float t = logf(P / (S + 1e-8f) + 1e-8f);
#pragma unroll
    for (int off = 32; off > 0; off >>= 1) t += __shfl_xor(t, off);
    __shared__ float red[4];
    if ((threadIdx.x & 63) == 0) red[threadIdx.x >> 6] = t;
    __syncthreads();
    if (threadIdx.x == 0) bsum[blockIdx.x] = red[0] + red[1] + red[2] + red[3];
}

__global__ void finalize(const float* __restrict__ bsum, float* __restrict__ loss) {
    float t = (threadIdx.x < 32) ? bsum[threadIdx.x] : 0.f;
#pragma unroll
    for (int off = 32; off > 0; off >>= 1) t += __shfl_xor(t, off);
    if (threadIdx.x == 0) *loss = -(t * (1.0f / 8192.0f));
}

// ---------------------------------------------------------------- launch
extern "C" void kernel_launch(void* const* d_in, const int* in_sizes, int n_in,
                              void* d_out, int out_size, void* d_ws, size_t ws_size,
                              hipStream_t stream) {
    const float* embd0 = (const float*)d_in[0];
    const float* embd1 = (const float*)d_in[1];
    const float* pos   = (const float*)d_in[2];
    const float* W1    = (const float*)d_in[3];
    const float* b1    = (const float*)d_in[4];
    const float* W2    = (const float*)d_in[5];
    const float* b2    = (const float*)d_in[6];
    float* out = (float*)d_out;  // [z0 | z1 | loss]

    char* ws = (char*)d_ws;
    bf16_t* Xb   = (bf16_t*)(ws);               // 16 MB  [16384][512]
    bf16_t* Hb   = (bf16_t*)(ws + 16777216);    // 16 MB
    bf16_t* Zb   = (bf16_t*)(ws + 33554432);    // 16 MB
    bf16_t* W1b  = (bf16_t*)(ws + 50331648);    // 512 KB
    bf16_t* W2b  = (bf16_t*)(ws + 50855936);    // 512 KB
    float*  rn   = (float*)(ws + 51380224);     // 64 KB (rn0|rn1)
    float*  pS   = (float*)(ws + 51445760);     // 2 MB [64][8192]
    float*  pP   = (float*)(ws + 53542912);     // 2 MB
    float*  bsum = (float*)(ws + 55640064);     // 128 B

    cvt_f32_bf16<<<2048, 256, 0, stream>>>(embd0, Xb, 524288);
    cvt_f32_bf16<<<2048, 256, 0, stream>>>(embd1, Xb + 4194304, 524288);
    cvt_f32_bf16<<<128, 256, 0, stream>>>(W1, W1b, 32768);
    cvt_f32_bf16<<<128, 256, 0, stream>>>(W2, W2b, 32768);

    gemm_bt<1><<<dim3(128, 4), 256, 0, stream>>>(Xb, W1b, b1, Hb, nullptr,
                                                 nullptr, nullptr, nullptr, nullptr, nullptr);
    gemm_bt<2><<<dim3(128, 4), 256, 0, stream>>>(Hb, W2b, b2, Zb, out,
                                                 nullptr, nullptr, nullptr, nullptr, nullptr);
    rownorm<<<4096, 256, 0, stream>>>(Zb, rn);
    gemm_bt<3><<<dim3(64, 64), 256, 0, stream>>>(Zb, Zb + 4194304, nullptr,
                                                 nullptr, nullptr, rn, rn + NROWS, pos,
                                                 pS, pP);
    reduce_rows<<<32, 256, 0, stream>>>(pS, pP, bsum);
    finalize<<<1, 64, 0, stream>>>(bsum, out + 8388608);
}